// Round 12
// baseline (16578.587 us; speedup 1.0000x reference)
//
#include <hip/hip_runtime.h>

// CustomLSTM  B=32, T=2048, H=512 (fp32 in/out)
// R12: 16 WGs x 512 thr (8 waves = 4 gates x 2 K-halves). WG j owns hidden
// cols [32j,32j+32) for all 4 gates, BOTH batch halves (P rows 0-15, Q 16-31)
// phase-interleaved R4-style so each half's LLC exchange hides under the
// other's compute. Narrower all-gather (16 flags, not 32) probes the
// straggler-tail theory of the ~6us exchange. V,U bf16 frags in VGPRs;
// x staged via swizzled LDS; counted vmcnt discipline; bounded polls.

#define BB 32
#define TT 2048
#define HH 512
#define NWG 16
#define HS (BB*TT*HH)

typedef short short8 __attribute__((ext_vector_type(8)));
typedef float floatx4 __attribute__((ext_vector_type(4)));

static __device__ __forceinline__ unsigned short f2bf(float f) {
  union { float f; unsigned u; } v; v.f = f;
  return (unsigned short)((v.u + 0x7FFFu + ((v.u >> 16) & 1u)) >> 16);
}
static __device__ __forceinline__ unsigned pk2(float a, float b) {
  return (unsigned)f2bf(a) | ((unsigned)f2bf(b) << 16);
}
static __device__ __forceinline__ float sigm(float z) { return 1.f / (1.f + __expf(-z)); }
static __device__ __forceinline__ float tanh_fast(float z) { return 1.f - 2.f / (__expf(2.f * z) + 1.f); }

static __device__ __forceinline__ unsigned long long aldq(const void* p) {
  return __hip_atomic_load((const unsigned long long*)p, __ATOMIC_RELAXED, __HIP_MEMORY_SCOPE_AGENT);
}
static __device__ __forceinline__ unsigned ald4(const void* p) {
  return __hip_atomic_load((const unsigned*)p, __ATOMIC_RELAXED, __HIP_MEMORY_SCOPE_AGENT);
}
static __device__ __forceinline__ void ast4(void* p, unsigned v) {
  __hip_atomic_store((unsigned*)p, v, __ATOMIC_RELAXED, __HIP_MEMORY_SCOPE_AGENT);
}
static __device__ __forceinline__ void ast2(void* p, unsigned short v) {
  __hip_atomic_store((unsigned short*)p, v, __ATOMIC_RELAXED, __HIP_MEMORY_SCOPE_AGENT);
}
static __device__ __forceinline__ void vwait0() {
  asm volatile("s_waitcnt vmcnt(0)" ::: "memory");
  __builtin_amdgcn_sched_barrier(0);
}
static __device__ __forceinline__ void vwait1() {
  asm volatile("s_waitcnt vmcnt(1)" ::: "memory");
  __builtin_amdgcn_sched_barrier(0);
}
static __device__ __forceinline__ void vwait8() {
  asm volatile("s_waitcnt vmcnt(8)" ::: "memory");
  __builtin_amdgcn_sched_barrier(0);
}
static __device__ __forceinline__ void lgkm0() {
  asm volatile("s_waitcnt lgkmcnt(0)" ::: "memory");
  __builtin_amdgcn_sched_barrier(0);
}
static __device__ __forceinline__ void rawbar() {
  __builtin_amdgcn_sched_barrier(0);
  __builtin_amdgcn_s_barrier();
  __builtin_amdgcn_sched_barrier(0);
}
static __device__ __forceinline__ void pollge(const unsigned* f, unsigned tgt, int lane) {
  const unsigned* p = f + (lane & 15);
  int it = 0;
  for (;;) {
    const unsigned v = ald4(p);
    if (__all((int)(v >= tgt))) break;
    if (++it > 16384) break;           // hang-proof
    __builtin_amdgcn_s_sleep(1);
  }
}

// h slots (bf16, frag order), 16KB each: P parity q at q*16384, Q at (2+q)*16384.
//   value (row er, col c): byte (c>>5)*1024 + ((((c>>3)&3)<<4)+er)*16 + (c&7)*2
//   consumer (wave sub): chunk kc = sub*8+kcl at kc*1024 + lane*16 (16B/lane).
// Flags at ws+65536: P = flags[0..15], Q = flags[64..79].

#define XFRAG(BROW, KC) \
  (*(const short8*)(lds_x + ((((BROW) * 1024) + (KC) * 64 + hi * 16) ^ (((BROW) & 7) << 4))))

__global__ __launch_bounds__(512, 1)
void lstm_kernel(const float* __restrict__ x,
                 const float* __restrict__ Ui, const float* __restrict__ Vi, const float* __restrict__ bi,
                 const float* __restrict__ Uf, const float* __restrict__ Vf, const float* __restrict__ bf,
                 const float* __restrict__ Uc, const float* __restrict__ Vc, const float* __restrict__ bc,
                 const float* __restrict__ Uo, const float* __restrict__ Vo, const float* __restrict__ bo,
                 float* __restrict__ out, unsigned char* __restrict__ ws)
{
  __shared__ __align__(16) unsigned char lds_x[BB * HH * 2];  // x(t) bf16 swizzled [32][512]
  __shared__ __align__(16) float glds[2][4][16][33];          // [Ksub][gate][row][col+pad]

  const int tid  = threadIdx.x;
  const int j    = blockIdx.x;
  const int wid  = tid >> 6;
  const int gt   = wid >> 1;           // gate 0..3 (i,f,c,o)
  const int sub  = wid & 1;            // K half
  const int lane = tid & 63;
  const int ln   = lane & 15;
  const int hi   = lane >> 4;
  const int j0   = j * 32;

  const float* Ug = (gt == 0) ? Ui : (gt == 1) ? Uf : (gt == 2) ? Uc : Uo;
  const float* Vg = (gt == 0) ? Vi : (gt == 1) ? Vf : (gt == 2) ? Vc : Vo;

  // ---- persistent bf16 weight frags: K in [sub*256,+256), cols 2 tiles of 16 ----
  short8 ufr[8][2], vfr[8][2];
#pragma unroll
  for (int kcl = 0; kcl < 8; ++kcl) {
#pragma unroll
    for (int ct = 0; ct < 2; ++ct) {
      short8 a, b;
#pragma unroll
      for (int i = 0; i < 8; ++i) {
        const int krow = (sub * 8 + kcl) * 32 + hi * 8 + i;
        const int col  = j0 + ct * 16 + ln;
        a[i] = (short)f2bf(Ug[(size_t)krow * HH + col]);
        b[i] = (short)f2bf(Vg[(size_t)krow * HH + col]);
      }
      ufr[kcl][ct] = a; vfr[kcl][ct] = b;
    }
  }

  // ---- EW mapping: 512 threads = 16 rows x 32 cols (1 cell per thread per half) ----
  const int er = tid >> 5;             // row within half
  const int cl = tid & 31;             // col-local
  const int ec = j0 + cl;              // global hidden col
  const float b0 = bi[ec], b1 = bf[ec], b2 = bc[ec], b3 = bo[ec];
  float cP = 0.f, cQ = 0.f;
  const int pboff = (ec >> 5) * 1024 + ((((ec >> 3) & 3) << 4) + er) * 16 + (ec & 7) * 2;

  unsigned* flagsP = (unsigned*)(ws + 65536);
  unsigned* flagsQ = (unsigned*)(ws + 65536) + 64;

  // ---- prologue: stage x(0) -> LDS, accU(0) for both halves ----
  float4 xr[8];
#pragma unroll
  for (int rr = 0; rr < 8; ++rr) {
    const int i = rr * 512 + tid;
    xr[rr] = *(const float4*)(x + (size_t)(i >> 7) * TT * HH + (i & 127) * 4);
  }
#pragma unroll
  for (int rr = 0; rr < 8; ++rr) {
    const int i = rr * 512 + tid;
    const int grow = i >> 7, c4 = i & 127;
    uint2 pkv; pkv.x = pk2(xr[rr].x, xr[rr].y); pkv.y = pk2(xr[rr].z, xr[rr].w);
    *(uint2*)(lds_x + ((grow * 1024 + c4 * 8) ^ ((grow & 7) << 4))) = pkv;
  }
  lgkm0();
  rawbar();
  floatx4 accU_P[2] = {{0.f,0.f,0.f,0.f},{0.f,0.f,0.f,0.f}};
  floatx4 accU_Q[2] = {{0.f,0.f,0.f,0.f},{0.f,0.f,0.f,0.f}};
#pragma unroll
  for (int kcl = 0; kcl < 8; ++kcl) {
    const int kc = sub * 8 + kcl;
    const short8 xfP = XFRAG(ln, kc);
    const short8 xfQ = XFRAG(16 + ln, kc);
    accU_P[0] = __builtin_amdgcn_mfma_f32_16x16x32_bf16(xfP, ufr[kcl][0], accU_P[0], 0, 0, 0);
    accU_P[1] = __builtin_amdgcn_mfma_f32_16x16x32_bf16(xfP, ufr[kcl][1], accU_P[1], 0, 0, 0);
    accU_Q[0] = __builtin_amdgcn_mfma_f32_16x16x32_bf16(xfQ, ufr[kcl][0], accU_Q[0], 0, 0, 0);
    accU_Q[1] = __builtin_amdgcn_mfma_f32_16x16x32_bf16(xfQ, ufr[kcl][1], accU_Q[1], 0, 0, 0);
  }

  short8 hreg[8];
#pragma unroll
  for (int kcl = 0; kcl < 8; ++kcl) hreg[kcl] = short8{0,0,0,0,0,0,0,0};

  for (int t = 0; t < TT; ++t) {
    const int par = t & 1;

    // ======== phase 1: MFMA P (hreg = hP(t-1), loaded in last shadowB) ========
    vwait0();                           // hP frag loads complete
    {
      floatx4 a0 = accU_P[0], a1 = accU_P[1];
      if (t > 0) {
#pragma unroll
        for (int kcl = 0; kcl < 8; ++kcl) {
          a0 = __builtin_amdgcn_mfma_f32_16x16x32_bf16(hreg[kcl], vfr[kcl][0], a0, 0, 0, 0);
          a1 = __builtin_amdgcn_mfma_f32_16x16x32_bf16(hreg[kcl], vfr[kcl][1], a1, 0, 0, 0);
        }
      }
#pragma unroll
      for (int r = 0; r < 4; ++r) {
        glds[sub][gt][hi * 4 + r][ln]      = a0[r];
        glds[sub][gt][hi * 4 + r][16 + ln] = a1[r];
      }
    }
    lgkm0();
    rawbar();   // B1

    // ======== phase 2: EW P + publish; then shadowA ========
    {
      const float z0 = glds[0][0][er][cl] + glds[1][0][er][cl] + b0;
      const float z1 = glds[0][1][er][cl] + glds[1][1][er][cl] + b1;
      const float z2 = glds[0][2][er][cl] + glds[1][2][er][cl] + b2;
      const float z3 = glds[0][3][er][cl] + glds[1][3][er][cl] + b3;
      const float ig = sigm(z0), fg = sigm(z1), gg = tanh_fast(z2), og = sigm(z3);
      cP = fg * cP + ig * gg;
      const float h = og * tanh_fast(cP);
      ast2(ws + (size_t)par * 16384 + pboff, f2bf(h));        // h publish first
      out[((size_t)er * TT + t) * HH + ec] = h;
      if (t == TT - 1) {
        out[(size_t)HS + er * HH + ec]           = h;
        out[(size_t)HS + BB * HH + er * HH + ec] = cP;
      }
    }
    vwait1();   // drain h store (out store still in flight)
    rawbar();   // B2
    if (tid == 0 && t + 1 < TT) ast4(flagsP + j, (unsigned)(t + 1));

    // shadowA: poll hQ(t-1) + load frags; issue x(ts) loads (ts clamped)
    if (t > 0) {
      pollge(flagsQ, (unsigned)t, lane);
      const unsigned char* sl = ws + (size_t)(2 + ((t - 1) & 1)) * 16384 + lane * 16;
#pragma unroll
      for (int kcl = 0; kcl < 8; ++kcl) {
        union { unsigned long long q[2]; short8 s; } u;
        u.q[0] = aldq(sl + (sub * 8 + kcl) * 1024);
        u.q[1] = aldq(sl + (sub * 8 + kcl) * 1024 + 8);
        hreg[kcl] = u.s;
      }
    }
    {
      const int ts = (t + 1 < TT) ? t + 1 : TT - 1;
#pragma unroll
      for (int rr = 0; rr < 8; ++rr) {
        const int i = rr * 512 + tid;
        xr[rr] = *(const float4*)(x + ((size_t)(i >> 7) * TT + ts) * HH + (i & 127) * 4);
      }
    }

    // ======== phase 3: MFMA Q (hreg = hQ(t-1)) ========
    vwait8();                           // hQ frags done; 8 x-loads may fly
    {
      floatx4 a0 = accU_Q[0], a1 = accU_Q[1];
      if (t > 0) {
#pragma unroll
        for (int kcl = 0; kcl < 8; ++kcl) {
          a0 = __builtin_amdgcn_mfma_f32_16x16x32_bf16(hreg[kcl], vfr[kcl][0], a0, 0, 0, 0);
          a1 = __builtin_amdgcn_mfma_f32_16x16x32_bf16(hreg[kcl], vfr[kcl][1], a1, 0, 0, 0);
        }
      }
#pragma unroll
      for (int r = 0; r < 4; ++r) {
        glds[sub][gt][hi * 4 + r][ln]      = a0[r];
        glds[sub][gt][hi * 4 + r][16 + ln] = a1[r];
      }
    }
    lgkm0();
    rawbar();   // B3

    // ======== phase 4: EW Q + publish; then shadowB + phase 5 ========
    {
      const float z0 = glds[0][0][er][cl] + glds[1][0][er][cl] + b0;
      const float z1 = glds[0][1][er][cl] + glds[1][1][er][cl] + b1;
      const float z2 = glds[0][2][er][cl] + glds[1][2][er][cl] + b2;
      const float z3 = glds[0][3][er][cl] + glds[1][3][er][cl] + b3;
      const float ig = sigm(z0), fg = sigm(z1), gg = tanh_fast(z2), og = sigm(z3);
      cQ = fg * cQ + ig * gg;
      const float h = og * tanh_fast(cQ);
      ast2(ws + (size_t)(2 + par) * 16384 + pboff, f2bf(h));
      out[((size_t)(16 + er) * TT + t) * HH + ec] = h;
      if (t == TT - 1) {
        out[(size_t)HS + (16 + er) * HH + ec]           = h;
        out[(size_t)HS + BB * HH + (16 + er) * HH + ec] = cQ;
      }
    }
    vwait1();   // drains x loads (needed by phase 5) + h store; out in flight
    rawbar();   // B4
    if (tid == 0 && t + 1 < TT) ast4(flagsQ + j, (unsigned)(t + 1));

    if (t + 1 < TT) {
      // shadowB: poll hP(t), issue hP frag loads (consumed at next phase 1)
      pollge(flagsP, (unsigned)(t + 1), lane);
      const unsigned char* sl = ws + (size_t)par * 16384 + lane * 16;
#pragma unroll
      for (int kcl = 0; kcl < 8; ++kcl) {
        union { unsigned long long q[2]; short8 s; } u;
        u.q[0] = aldq(sl + (sub * 8 + kcl) * 1024);
        u.q[1] = aldq(sl + (sub * 8 + kcl) * 1024 + 8);
        hreg[kcl] = u.s;
      }

      // phase 5: restage x(t+1) -> LDS, rebuild accU(t+1) (hP loads in flight)
#pragma unroll
      for (int rr = 0; rr < 8; ++rr) {
        const int i = rr * 512 + tid;
        const int grow = i >> 7, c4 = i & 127;
        uint2 pkv; pkv.x = pk2(xr[rr].x, xr[rr].y); pkv.y = pk2(xr[rr].z, xr[rr].w);
        *(uint2*)(lds_x + ((grow * 1024 + c4 * 8) ^ ((grow & 7) << 4))) = pkv;
      }
      lgkm0();
      rawbar();   // B5: lds_x restaged
      floatx4 p0 = {0.f,0.f,0.f,0.f}, p1 = {0.f,0.f,0.f,0.f};
      floatx4 q0 = {0.f,0.f,0.f,0.f}, q1 = {0.f,0.f,0.f,0.f};
#pragma unroll
      for (int kcl = 0; kcl < 8; ++kcl) {
        const int kc = sub * 8 + kcl;
        const short8 xfP = XFRAG(ln, kc);
        const short8 xfQ = XFRAG(16 + ln, kc);
        p0 = __builtin_amdgcn_mfma_f32_16x16x32_bf16(xfP, ufr[kcl][0], p0, 0, 0, 0);
        p1 = __builtin_amdgcn_mfma_f32_16x16x32_bf16(xfP, ufr[kcl][1], p1, 0, 0, 0);
        q0 = __builtin_amdgcn_mfma_f32_16x16x32_bf16(xfQ, ufr[kcl][0], q0, 0, 0, 0);
        q1 = __builtin_amdgcn_mfma_f32_16x16x32_bf16(xfQ, ufr[kcl][1], q1, 0, 0, 0);
      }
      accU_P[0] = p0; accU_P[1] = p1; accU_Q[0] = q0; accU_Q[1] = q1;
    }
  }
}

extern "C" void kernel_launch(void* const* d_in, const int* in_sizes, int n_in,
                              void* d_out, int out_size, void* d_ws, size_t ws_size,
                              hipStream_t stream) {
  (void)in_sizes; (void)n_in; (void)out_size; (void)ws_size;
  const float* x  = (const float*)d_in[0];
  const float* Ui = (const float*)d_in[1];
  const float* Vi = (const float*)d_in[2];
  const float* bi = (const float*)d_in[3];
  const float* Uf = (const float*)d_in[4];
  const float* Vf = (const float*)d_in[5];
  const float* bf = (const float*)d_in[6];
  const float* Uc = (const float*)d_in[7];
  const float* Vc = (const float*)d_in[8];
  const float* bc = (const float*)d_in[9];
  const float* Uo = (const float*)d_in[10];
  const float* Vo = (const float*)d_in[11];
  const float* bo = (const float*)d_in[12];

  // zero flags each launch (h slots are flag-gated)
  hipMemsetAsync((char*)d_ws + 65536, 0, 512, stream);

  lstm_kernel<<<dim3(NWG), dim3(512), 0, stream>>>(
      x, Ui, Vi, bi, Uf, Vf, bf, Uc, Vc, bc, Uo, Vo, bo,
      (float*)d_out, (unsigned char*)d_ws);
}

// Round 13
// 11303.111 us; speedup vs baseline: 1.4667x; 1.4667x over previous
//
#include <hip/hip_runtime.h>

// CustomLSTM  B=32, T=2048, H=512 (fp32 in/out)
// R13 = R4 (proven 10.7ms) + same-XCD fast path.
// 256 blocks launched; XCC_ID election selects 32 blocks on ONE XCD (rest
// exit). Two-phase nonce probe verifies shared-L2 coherence (phase 2 catches
// stale-clean lines: cross-XCD members cached phase-1 value and MUST fail).
// fast mode: h/flags via plain stores (write-through to the shared L2) +
// sc0 (L1-bypass) loads. agent mode: R4 verbatim (LLC). Output identical.

#define BB 32
#define TT 2048
#define HH 512
#define NWG 32
#define HS (BB*TT*HH)

typedef short short8 __attribute__((ext_vector_type(8)));
typedef float floatx4 __attribute__((ext_vector_type(4)));

static __device__ __forceinline__ unsigned short f2bf(float f) {
  union { float f; unsigned u; } v; v.f = f;
  return (unsigned short)((v.u + 0x7FFFu + ((v.u >> 16) & 1u)) >> 16);
}
static __device__ __forceinline__ unsigned pk2(float a, float b) {
  return (unsigned)f2bf(a) | ((unsigned)f2bf(b) << 16);
}
static __device__ __forceinline__ float sigm(float z) { return 1.f / (1.f + __expf(-z)); }
static __device__ __forceinline__ float tanh_fast(float z) { return 1.f - 2.f / (__expf(2.f * z) + 1.f); }

static __device__ __forceinline__ unsigned long long aldq(const void* p) {
  return __hip_atomic_load((const unsigned long long*)p, __ATOMIC_RELAXED, __HIP_MEMORY_SCOPE_AGENT);
}
static __device__ __forceinline__ unsigned agld(const unsigned* p) {
  return __hip_atomic_load(p, __ATOMIC_RELAXED, __HIP_MEMORY_SCOPE_AGENT);
}
static __device__ __forceinline__ void ast4(unsigned* p, unsigned v) {
  __hip_atomic_store(p, v, __ATOMIC_RELAXED, __HIP_MEMORY_SCOPE_AGENT);
}
static __device__ __forceinline__ unsigned ld_sc0dw(const void* p) {
  unsigned r;
  asm volatile("global_load_dword %0, %1, off sc0\n\ts_waitcnt vmcnt(0)"
               : "=v"(r) : "v"(p) : "memory");
  __builtin_amdgcn_sched_barrier(0);
  return r;
}
static __device__ __forceinline__ void ld16_sc0_nw(int4& d, const void* p) {
  asm volatile("global_load_dwordx4 %0, %1, off sc0" : "=v"(d) : "v"(p) : "memory");
}
static __device__ __forceinline__ void rawbar() {
  __builtin_amdgcn_sched_barrier(0);
  __builtin_amdgcn_s_barrier();
  __builtin_amdgcn_sched_barrier(0);
}

#define LOADF(IDX) __hip_atomic_load(&flags[(IDX)], __ATOMIC_RELAXED, __HIP_MEMORY_SCOPE_AGENT)

// load x(TSTEP) rows HALFBASE..+15 into XR (waves 2-7: 384 thr x up-to-6 float4)
#define LOAD_X(XR, HALFBASE, TSTEP)                                              \
    if (tid >= 128) {                                                            \
      _Pragma("unroll")                                                          \
      for (int rr = 0; rr < 6; ++rr) {                                           \
        const int i = rr * 384 + sx;                                             \
        if (i < 2048) {                                                          \
          const int grow = (HALFBASE) + (i >> 7), c4 = i & 127;                  \
          XR[rr] = *(const float4*)(x + ((size_t)grow * TT + (TSTEP)) * HH + c4 * 4); \
        }                                                                        \
      }                                                                          \
    }

#define STAGE_X(XR, HALFBASE)                                                    \
    if (tid >= 128) {                                                            \
      _Pragma("unroll")                                                          \
      for (int rr = 0; rr < 6; ++rr) {                                           \
        const int i = rr * 384 + sx;                                             \
        if (i < 2048) {                                                          \
          const int grow = (HALFBASE) + (i >> 7), c4 = i & 127;                  \
          uint2 p; p.x = pk2(XR[rr].x, XR[rr].y); p.y = pk2(XR[rr].z, XR[rr].w); \
          *(uint2*)(lds_x + ((grow * 1024 + c4 * 8) ^ ((grow & 7) << 4))) = p;   \
        }                                                                        \
      }                                                                          \
    }

// elementwise LSTM cell for one batch half (tid<128), mode-aware h store
#define EW_PHASE(HALF, C0, C1, SLOTPTR)                                          \
    if (tid < 128) {                                                             \
      const int er = tid >> 3, ec = (tid & 7) * 2;                               \
      float zz[4][2];                                                            \
      _Pragma("unroll")                                                          \
      for (int g = 0; g < 4; ++g) {                                              \
        zz[g][0] = gates[0][g][er][ec]     + gates[1][g][er][ec]     + bia[g][0];\
        zz[g][1] = gates[0][g][er][ec + 1] + gates[1][g][er][ec + 1] + bia[g][1];\
      }                                                                          \
      const float i0 = sigm(zz[0][0]), i1 = sigm(zz[0][1]);                      \
      const float f0 = sigm(zz[1][0]), f1 = sigm(zz[1][1]);                      \
      const float g0 = tanh_fast(zz[2][0]), g1 = tanh_fast(zz[2][1]);            \
      const float o0 = sigm(zz[3][0]), o1 = sigm(zz[3][1]);                      \
      C0 = f0 * C0 + i0 * g0;  C1 = f1 * C1 + i1 * g1;                           \
      const float h0 = o0 * tanh_fast(C0), h1 = o1 * tanh_fast(C1);              \
      const int gc = j0 + ec;                                                    \
      *(float2*)(out + ((size_t)((HALF)*16 + er) * TT + t) * HH + gc) =          \
          make_float2(h0, h1);                                                   \
      const int uidx = (((gc >> 5) * 64 + ((gc >> 3) & 3) * 16 + er) * 4) + ((gc & 7) >> 1); \
      unsigned* hw_ = (unsigned*)(SLOTPTR) + uidx;                               \
      if (fastm) *(volatile unsigned*)hw_ = pk2(h0, h1);                         \
      else __hip_atomic_store(hw_, pk2(h0, h1),                                  \
                              __ATOMIC_RELAXED, __HIP_MEMORY_SCOPE_AGENT);       \
      if (t == TT - 1) {                                                         \
        const int b = (HALF)*16 + er;                                            \
        out[(size_t)HS + b * HH + gc]               = h0;                        \
        out[(size_t)HS + b * HH + gc + 1]           = h1;                        \
        out[(size_t)HS + BB * HH + b * HH + gc]     = C0;                        \
        out[(size_t)HS + BB * HH + b * HH + gc + 1] = C1;                        \
      }                                                                          \
    }

__global__ __launch_bounds__(512, 1)
void lstm_kernel(const float* __restrict__ x,
                 const float* __restrict__ Ui, const float* __restrict__ Vi, const float* __restrict__ bi,
                 const float* __restrict__ Uf, const float* __restrict__ Vf, const float* __restrict__ bf,
                 const float* __restrict__ Uc, const float* __restrict__ Vc, const float* __restrict__ bc,
                 const float* __restrict__ Uo, const float* __restrict__ Vo, const float* __restrict__ bo,
                 float* __restrict__ out, unsigned char* __restrict__ ws)
{
  __shared__ __align__(16) unsigned char lds_x[BB * HH * 2];  // x(t) bf16 swizzled [32][512]
  __shared__ __align__(16) float gates[2][4][16][18];
  __shared__ int s_rank, s_win, s_fast;

  const int tid = threadIdx.x;
  unsigned long long* hbuf = (unsigned long long*)ws;          // 4 x 16KB h slots
  unsigned* flags = (unsigned*)(ws + 65536);                   // P[0..31], Q[32..63]
  unsigned* ectl  = (unsigned*)(ws + 66048);                   // election/probe state

  // ================= election: pick 32 co-XCD blocks =================
  int xcc;
  asm volatile("s_getreg_b32 %0, hwreg(HW_REG_XCC_ID)" : "=s"(xcc));
  xcc &= 7;
  if (tid == 0) {
    const int r = (int)atomicAdd(&ectl[xcc], 1u);
    s_rank = r;
    if (r == NWG - 1) atomicCAS(&ectl[8], 0u, (unsigned)(xcc + 1));
  }
  __syncthreads();
  const int rank = s_rank;
  __syncthreads();
  if (tid == 0) {
    unsigned w = 0; int it = 0;
    while ((w = agld(&ectl[8])) == 0u && ++it < (1 << 20)) __builtin_amdgcn_s_sleep(8);
    s_win = (int)w - 1;                 // -1 on timeout
  }
  __syncthreads();
  const int win = s_win;
  int wg;
  bool member;
  if (win >= 0) { member = (xcc == win) && (rank < NWG); wg = rank; }
  else          { member = ((int)blockIdx.x < NWG);      wg = (int)blockIdx.x; }
  if (!member) return;

  // ================= two-phase coherence probe -> mode =================
  int fastm = 0;
  if (win >= 0) {
    if (tid == 0) {
      volatile unsigned* probe = (volatile unsigned*)(ws + 66560);
      unsigned n1 = 0, n2 = 0; int it;
      if (wg == 0) {
        n1 = ((unsigned)__builtin_amdgcn_s_memrealtime() << 2) | 1u;
        *probe = n1;                                   // plain store -> L2
        asm volatile("s_waitcnt vmcnt(0)" ::: "memory");
        ast4(&ectl[11], n1);                           // expected value via LLC
      }
      it = 0; while ((n1 = agld(&ectl[11])) == 0u && ++it < (1 << 20)) __builtin_amdgcn_s_sleep(8);
      int ok1 = 0;                                     // phase 1: warm (MALL ok)
      for (it = 0; it < 4096 && !ok1; ++it)
        if (ld_sc0dw((const void*)probe) == n1) ok1 = 1;
      __hip_atomic_fetch_add(&ectl[13], 1u, __ATOMIC_RELAXED, __HIP_MEMORY_SCOPE_AGENT);
      if (wg == 0) {
        it = 0; while (agld(&ectl[13]) < (unsigned)NWG && ++it < (1 << 20)) __builtin_amdgcn_s_sleep(4);
        n2 = n1 + 2u;
        *probe = n2;                                   // update: stale-clean test
        asm volatile("s_waitcnt vmcnt(0)" ::: "memory");
        ast4(&ectl[12], n2);
      }
      it = 0; while ((n2 = agld(&ectl[12])) == 0u && ++it < (1 << 20)) __builtin_amdgcn_s_sleep(8);
      int ok2 = 0;                                     // phase 2: must be FAST
      for (it = 0; it < 256 && !ok2; ++it)
        if (ld_sc0dw((const void*)probe) == n2) ok2 = 1;
      if (ok1 && ok2) __hip_atomic_fetch_add(&ectl[9],  1u, __ATOMIC_RELAXED, __HIP_MEMORY_SCOPE_AGENT);
      __hip_atomic_fetch_add(&ectl[10], 1u, __ATOMIC_RELAXED, __HIP_MEMORY_SCOPE_AGENT);
      it = 0; while (agld(&ectl[10]) < (unsigned)NWG && ++it < (1 << 20)) __builtin_amdgcn_s_sleep(4);
      s_fast = (agld(&ectl[9]) == (unsigned)NWG) ? 1 : 0;
    }
    __syncthreads();
    fastm = s_fast;
  }

  // ================= R4 worker (verbatim except mode ops) =================
  const int lane = tid & 63;
  const int wid  = tid >> 6;
  const int sub  = wid & 1;
  const int gt   = wid >> 1;
  const int j0   = wg * 16;
  const int ln   = lane & 15;
  const int hi   = lane >> 4;
  const int sx   = tid - 128;
  const int xsw  = (ln & 7) << 4;
  const int hfb  = sub * 1024 + lane * 2;   // ull index into h slot

  const float* Ug = (gt == 0) ? Ui : (gt == 1) ? Uf : (gt == 2) ? Uc : Uo;
  const float* Vg = (gt == 0) ? Vi : (gt == 1) ? Vf : (gt == 2) ? Vc : Vo;

  short8 ufr[8], vfr[8];
#pragma unroll
  for (int kcl = 0; kcl < 8; ++kcl) {
    short8 a, b;
#pragma unroll
    for (int i = 0; i < 8; ++i) {
      const int krow = (sub * 8 + kcl) * 32 + hi * 8 + i;
      a[i] = (short)f2bf(Ug[(size_t)krow * HH + j0 + ln]);
      b[i] = (short)f2bf(Vg[(size_t)krow * HH + j0 + ln]);
    }
    ufr[kcl] = a; vfr[kcl] = b;
  }

  float bia[4][2];
  float cP0 = 0.f, cP1 = 0.f, cQ0 = 0.f, cQ1 = 0.f;
  if (tid < 128) {
    const int ec = (tid & 7) * 2;
    bia[0][0] = bi[j0 + ec]; bia[0][1] = bi[j0 + ec + 1];
    bia[1][0] = bf[j0 + ec]; bia[1][1] = bf[j0 + ec + 1];
    bia[2][0] = bc[j0 + ec]; bia[2][1] = bc[j0 + ec + 1];
    bia[3][0] = bo[j0 + ec]; bia[3][1] = bo[j0 + ec + 1];
  }

  // ---- stage x(0), all 32 rows ----
#pragma unroll
  for (int rr = 0; rr < 8; ++rr) {
    const int i = rr * 512 + tid;
    const int grow = i >> 7, c4 = i & 127;
    const float4 v = *(const float4*)(x + (size_t)grow * TT * HH + c4 * 4);
    uint2 p; p.x = pk2(v.x, v.y); p.y = pk2(v.z, v.w);
    *(uint2*)(lds_x + ((grow * 1024 + c4 * 8) ^ ((grow & 7) << 4))) = p;
  }
  float4 xa[6], xb[6];
  LOAD_X(xa, 0, 1)
  __syncthreads();

  union HU { unsigned long long q[2]; int4 v; short8 s; };
  HU hreg[8];
  unsigned fP = 0, fQ = 0;

  for (int t = 0; t < TT; ++t) {
    const int par = t & 1;
    if (t > 0 && !fastm) fQ = LOADF(32 + (lane & 31));
    if (t + 1 < TT) LOAD_X(xb, 16, t + 1)

    // ======== phase 1: MFMA half P ========
    floatx4 acc = {0.f, 0.f, 0.f, 0.f};
#pragma unroll
    for (int kcl = 0; kcl < 8; ++kcl) {
      const int kc = sub * 8 + kcl;
      const short8 xf = *(const short8*)(lds_x + ((ln * 1024 + kc * 64 + hi * 16) ^ xsw));
      acc = __builtin_amdgcn_mfma_f32_16x16x32_bf16(xf, ufr[kcl], acc, 0, 0, 0);
    }
    if (t > 0) {
#pragma unroll
      for (int kcl = 0; kcl < 8; ++kcl)
        acc = __builtin_amdgcn_mfma_f32_16x16x32_bf16(hreg[kcl].s, vfr[kcl], acc, 0, 0, 0);
    }
#pragma unroll
    for (int rg = 0; rg < 4; ++rg) gates[sub][gt][hi * 4 + rg][ln] = acc[rg];
    __syncthreads();   // B1

    // ---- shadow A: confirm Q flags + prefetch hQ(t-1) ----
    if (t > 0) {
      if (fastm) {
        if (tid < 128) {
          const unsigned tq = (unsigned)t; int itc = 0;
          for (;;) {
            const unsigned v = ld_sc0dw(&flags[32 + (lane & 31)]);
            if (__all((int)(v >= tq))) break;
            if (++itc > (1 << 20)) break;
            __builtin_amdgcn_s_sleep(1);
          }
        }
        rawbar();
        const unsigned char* hq =
            (const unsigned char*)(hbuf + (size_t)(2 + ((t - 1) & 1)) * 2048);
#pragma unroll
        for (int kcl = 0; kcl < 8; ++kcl)
          ld16_sc0_nw(hreg[kcl].v, hq + (size_t)(hfb + kcl * 128) * 8);
        // results fenced by __syncthreads C1 (vmcnt 0) before use in phase 3
      } else {
        const unsigned tq = (unsigned)t; int itc = 0;
        while (!__all((int)(fQ >= tq))) {
          __builtin_amdgcn_s_sleep(1);
          fQ = LOADF(32 + (lane & 31));
          if (++itc > (1 << 20)) break;
        }
        const unsigned long long* hq = hbuf + (size_t)(2 + ((t - 1) & 1)) * 2048;
#pragma unroll
        for (int kcl = 0; kcl < 8; ++kcl) {
          hreg[kcl].q[0] = aldq(hq + hfb + kcl * 128);
          hreg[kcl].q[1] = aldq(hq + hfb + kcl * 128 + 1);
        }
      }
    }

    EW_PHASE(0, cP0, cP1, hbuf + (size_t)par * 2048)   // ew P + store hP(t)
    if (t + 1 < TT) STAGE_X(xa, 0)
    __syncthreads();   // C1: hP stores (+fast hQ loads) drained
    if (tid == 0 && t + 1 < TT) {
      if (fastm) *(volatile unsigned*)&flags[wg] = (unsigned)(t + 1);
      else       ast4(&flags[wg], (unsigned)(t + 1));
    }

    // ======== phase 3: MFMA half Q ========
    acc = (floatx4){0.f, 0.f, 0.f, 0.f};
#pragma unroll
    for (int kcl = 0; kcl < 8; ++kcl) {
      const int kc = sub * 8 + kcl;
      const short8 xf = *(const short8*)(lds_x + (((16 + ln) * 1024 + kc * 64 + hi * 16) ^ xsw));
      acc = __builtin_amdgcn_mfma_f32_16x16x32_bf16(xf, ufr[kcl], acc, 0, 0, 0);
    }
    if (t > 0) {
#pragma unroll
      for (int kcl = 0; kcl < 8; ++kcl)
        acc = __builtin_amdgcn_mfma_f32_16x16x32_bf16(hreg[kcl].s, vfr[kcl], acc, 0, 0, 0);
    }
    if (t + 1 < TT && !fastm) fP = LOADF(lane & 31);
#pragma unroll
    for (int rg = 0; rg < 4; ++rg) gates[sub][gt][hi * 4 + rg][ln] = acc[rg];
    __syncthreads();   // B2

    EW_PHASE(1, cQ0, cQ1, hbuf + (size_t)(2 + par) * 2048)  // ew Q + store hQ(t)
    if (t + 1 < TT) STAGE_X(xb, 16)
    __syncthreads();   // C2
    if (tid == 0 && t + 1 < TT) {
      if (fastm) *(volatile unsigned*)&flags[32 + wg] = (unsigned)(t + 1);
      else       ast4(&flags[32 + wg], (unsigned)(t + 1));
    }

    // ======== phase 5: confirm P flags, prefetch hP(t); pre-issue x(t+2) ========
    if (t + 1 < TT) {
      if (fastm) {
        if (tid < 128) {
          const unsigned tp = (unsigned)(t + 1); int itc = 0;
          for (;;) {
            const unsigned v = ld_sc0dw(&flags[lane & 31]);
            if (__all((int)(v >= tp))) break;
            if (++itc > (1 << 20)) break;
            __builtin_amdgcn_s_sleep(1);
          }
        }
        rawbar();
        const unsigned char* hp = (const unsigned char*)(hbuf + (size_t)par * 2048);
#pragma unroll
        for (int kcl = 0; kcl < 8; ++kcl)
          ld16_sc0_nw(hreg[kcl].v, hp + (size_t)(hfb + kcl * 128) * 8);
        // fenced by next iteration's B1 __syncthreads before phase-1 use
      } else {
        const unsigned tp = (unsigned)(t + 1); int itc = 0;
        while (!__all((int)(fP >= tp))) {
          __builtin_amdgcn_s_sleep(1);
          fP = LOADF(lane & 31);
          if (++itc > (1 << 20)) break;
        }
        const unsigned long long* hp = hbuf + (size_t)par * 2048;
#pragma unroll
        for (int kcl = 0; kcl < 8; ++kcl) {
          hreg[kcl].q[0] = aldq(hp + hfb + kcl * 128);
          hreg[kcl].q[1] = aldq(hp + hfb + kcl * 128 + 1);
        }
      }
      if (t + 2 < TT) LOAD_X(xa, 0, t + 2)
    }
  }
}

extern "C" void kernel_launch(void* const* d_in, const int* in_sizes, int n_in,
                              void* d_out, int out_size, void* d_ws, size_t ws_size,
                              hipStream_t stream) {
  (void)in_sizes; (void)n_in; (void)out_size; (void)ws_size;
  const float* x  = (const float*)d_in[0];
  const float* Ui = (const float*)d_in[1];
  const float* Vi = (const float*)d_in[2];
  const float* bi = (const float*)d_in[3];
  const float* Uf = (const float*)d_in[4];
  const float* Vf = (const float*)d_in[5];
  const float* bf = (const float*)d_in[6];
  const float* Uc = (const float*)d_in[7];
  const float* Vc = (const float*)d_in[8];
  const float* bc = (const float*)d_in[9];
  const float* Uo = (const float*)d_in[10];
  const float* Vo = (const float*)d_in[11];
  const float* bo = (const float*)d_in[12];

  // zero flags + election/probe state (h slots are flag-gated, no reset)
  hipMemsetAsync((char*)d_ws + 65536, 0, 4096, stream);

  lstm_kernel<<<dim3(256), dim3(512), 0, stream>>>(
      x, Ui, Vi, bi, Uf, Vf, bf, Uc, Vc, bc, Uo, Vo, bo,
      (float*)d_out, (unsigned char*)d_ws);
}